// Round 8
// baseline (7179.997 us; speedup 1.0000x reference)
//
#include <hip/hip_runtime.h>

#define B_SZ 512
#define T_SZ 256
#define D_SZ 256
#define U_SZ 512

typedef float  f32x4  __attribute__((ext_vector_type(4)));
typedef short  short8 __attribute__((ext_vector_type(8)));
typedef __bf16 bf16x8 __attribute__((ext_vector_type(8)));

static __device__ __forceinline__ unsigned short f2bf(float f) {
  unsigned u = __builtin_bit_cast(unsigned, f);
  return (unsigned short)((u + 0x7FFFu + ((u >> 16) & 1u)) >> 16);
}

static __device__ __forceinline__ f32x4 mfma_bf16(short8 a, short8 b, f32x4 c) {
  return __builtin_amdgcn_mfma_f32_16x16x32_bf16(
      __builtin_bit_cast(bf16x8, a), __builtin_bit_cast(bf16x8, b), c, 0, 0, 0);
}

static __device__ __forceinline__ float sigm(float x) {
  return 1.f / (1.f + __expf(-x));
}
static __device__ __forceinline__ float tanh_fast(float x) {
  return 1.f - 2.f / (__expf(2.f * x) + 1.f);  // safe at +/-inf
}

// ---------------- K1: transpose-cast weights into Wt[2048 cols][768 k] bf16 ----
__global__ __launch_bounds__(256) void wt_kernel(const float* __restrict__ Wx,
                                                 const float* __restrict__ Wh,
                                                 unsigned short* __restrict__ Wt) {
  __shared__ float tile[32][33];
  const int ct = blockIdx.x;       // col tile (64)
  const int kt = blockIdx.y;       // k tile (24)
  const int tx = threadIdx.x & 31;
  const int ty = threadIdx.x >> 5; // 0..7
  const int k0 = kt * 32;
#pragma unroll
  for (int q = 0; q < 4; ++q) {
    int kl = ty + q * 8;
    int kg = k0 + kl;
    float v = (kg < 256) ? Wx[(size_t)kg * 2048 + ct * 32 + tx]
                         : Wh[(size_t)(kg - 256) * 2048 + ct * 32 + tx];
    tile[kl][tx] = v;
  }
  __syncthreads();
#pragma unroll
  for (int q = 0; q < 4; ++q) {
    int cl = ty + q * 8;
    Wt[(size_t)(ct * 32 + cl) * 768 + k0 + tx] = f2bf(tile[tx][cl]);
  }
}

// ---------------- K2: persistent fused LSTM, 4 chains per WG -------------------
// grid = 64 WGs x 256 thr. Pair-group P = blk&7 (XCD-co-located), strip
// s = blk>>3 (8 strips x 64 u). Each WG time-interleaves 4 INDEPENDENT
// recurrence chains (rowgroups P*4+c, 16 rows each) sharing the same
// register-resident weight strip (384 VGPRs: 24 kt x 4 gates, 16 u/wave).
// While chain c waits on its cross-WG flags, the other 3 chains compute ->
// handshake latency (the measured ~7.4us/step stall) hides behind ~3 chain-
// computes. Cross-WG h exchange: relaxed agent-scope atomics (L3-coherent,
// no fences, no L2 invalidation); ordering via __syncthreads vmcnt drain
// before flag publish. LDS 96KB = 4 chains x (x 8KB + h 16KB), XOR-swizzled.
__global__ __launch_bounds__(256, 1) void lstm_kernel(
    const float* __restrict__ x, const unsigned short* __restrict__ Wt,
    const float* __restrict__ bias, unsigned short* __restrict__ hbuf,
    unsigned* __restrict__ flags, float* __restrict__ hfin) {
  extern __shared__ char smem[];
  const int tid  = threadIdx.x;
  const int lane = tid & 63;
  const int wv   = tid >> 6;            // 0..3 = u-quarter of the strip
  const int P    = blockIdx.x & 7;      // pair-group (XCD heuristic)
  const int s    = blockIdx.x >> 3;     // strip 0..7 (64 u each)
  const int col  = lane & 15;
  const int kgrp = lane >> 4;           // 0..3
  const int ug   = s * 64 + wv * 16 + col;  // global u column

  // ---- wave's B strip in registers: 24 kt x 4 gates (shared by all chains) --
  short8 Bfr[96];
#pragma unroll
  for (int kt = 0; kt < 24; ++kt) {
#pragma unroll
    for (int gg = 0; gg < 4; ++gg) {
      const unsigned short* p =
          Wt + (size_t)(gg * 512 + ug) * 768 + kgrp * 8 + kt * 32;
      Bfr[kt * 4 + gg] = *(const short8*)p;
    }
  }
  float bias_g[4];
#pragma unroll
  for (int gg = 0; gg < 4; ++gg) bias_g[gg] = bias[gg * 512 + ug];

  f32x4 cst[4];
#pragma unroll
  for (int c = 0; c < 4; ++c) cst[c] = (f32x4){0.f, 0.f, 0.f, 0.f};

  int p = 0;
  for (int t = 0; t < 256; ++t) {
#pragma unroll
    for (int c = 0; c < 4; ++c) {       // 4 independent chains, static unroll
      const int RG = P * 4 + c;         // rowgroup 0..31 (16 rows)
      const unsigned cbase = (unsigned)c * 24576u;

      // ---- wait: lanes 0..7 poll the 8 strip flags of (RG, t-1) ----
      if (t > 0) {
        const unsigned* fb = flags + ((((unsigned)RG << 8) + (t - 1)) << 3);
        if (lane < 8) {
          while (__hip_atomic_load(fb + lane, __ATOMIC_RELAXED,
                                   __HIP_MEMORY_SCOPE_AGENT) == 0u) {
          }
        }
        __builtin_amdgcn_sched_barrier(0);
      }

      // ---- stage x_t (f32 cached loads -> bf16, swizzled) ----
#pragma unroll
      for (int i = 0; i < 2; ++i) {     // 512 chunks of 8 f32
        int ch = tid + i * 256;
        int row = ch >> 5;
        int k0 = (ch & 31) * 8;
        const float* xp =
            x + ((size_t)(RG * 16 + row) * T_SZ + t) * D_SZ + k0;
        float4 a  = *(const float4*)xp;
        float4 b2 = *(const float4*)(xp + 4);
        short8 v;
        v[0] = (short)f2bf(a.x);  v[1] = (short)f2bf(a.y);
        v[2] = (short)f2bf(a.z);  v[3] = (short)f2bf(a.w);
        v[4] = (short)f2bf(b2.x); v[5] = (short)f2bf(b2.y);
        v[6] = (short)f2bf(b2.z); v[7] = (short)f2bf(b2.w);
        unsigned byte =
            (cbase + (unsigned)(row * 512 + k0 * 2)) ^ ((row & 7) << 4);
        *(short8*)(smem + byte) = v;
      }
      // ---- stage h_{t-1} (relaxed agent u64 loads from L3, swizzled) ----
      const unsigned short* hr =
          hbuf + ((size_t)p << 18) + ((size_t)(RG * 16) << 9);
#pragma unroll
      for (int i = 0; i < 8; ++i) {     // 2048 u64 chunks (4 bf16 each)
        int ch = tid + i * 256;
        int row = ch >> 7;
        int c4 = ch & 127;
        const unsigned long long* hp =
            (const unsigned long long*)(hr + ((size_t)row << 9) + c4 * 4);
        unsigned long long v = __hip_atomic_load(hp, __ATOMIC_RELAXED,
                                                 __HIP_MEMORY_SCOPE_AGENT);
        unsigned byte = (cbase + 8192u + (unsigned)(row * 1024 + c4 * 8)) ^
                        ((row & 7) << 4);
        *(unsigned long long*)(smem + byte) = v;
      }
      __syncthreads();

      // ---- GEMM: z[16 rows x 64 z-cols] per wave, weights from regs ----
      f32x4 acc[4];
#pragma unroll
      for (int gg = 0; gg < 4; ++gg) acc[gg] = (f32x4){0.f, 0.f, 0.f, 0.f};
      const int arow = col;             // M=16: A row = lane&15
      const unsigned rsw = (unsigned)((arow & 7) << 4);
#pragma unroll
      for (int kt = 0; kt < 24; ++kt) {
        unsigned byte;
        if (kt < 8)
          byte = (cbase + (unsigned)(arow * 512 + kt * 64 + kgrp * 16)) ^ rsw;
        else
          byte = (cbase + 8192u +
                  (unsigned)(arow * 1024 + (kt - 8) * 64 + kgrp * 16)) ^ rsw;
        short8 af = *(const short8*)(smem + byte);
        acc[0] = mfma_bf16(af, Bfr[kt * 4 + 0], acc[0]);
        acc[1] = mfma_bf16(af, Bfr[kt * 4 + 1], acc[1]);
        acc[2] = mfma_bf16(af, Bfr[kt * 4 + 2], acc[2]);
        acc[3] = mfma_bf16(af, Bfr[kt * 4 + 3], acc[3]);
      }

      // ---- gates + state update (lane-local) ----
#pragma unroll
      for (int j = 0; j < 4; ++j) {
        float zi = acc[0][j] + bias_g[0];
        float zf = acc[1][j] + bias_g[1];
        float zg = acc[2][j] + bias_g[2];
        float zo = acc[3][j] + bias_g[3];
        float ii = sigm(zi);
        float ff = sigm(zf);
        float gv = tanh_fast(zg);
        float oo = sigm(zo);
        float cv = ff * cst[c][j] + ii * gv;
        cst[c][j] = cv;
        float hv = oo * tanh_fast(cv);
        int brow = RG * 16 + kgrp * 4 + j;
        if (t == 255) {
          hfin[(size_t)brow * 512 + ug] = hv;
        } else {
          unsigned short* hp =
              hbuf + (((size_t)(p ^ 1)) << 18) + ((size_t)brow << 9) + ug;
          __hip_atomic_store(hp, f2bf(hv), __ATOMIC_RELAXED,
                             __HIP_MEMORY_SCOPE_AGENT);
        }
      }

      // ---- arrive: syncthreads drains vmcnt (h stores), then publish ----
      if (t < 255) {
        __syncthreads();
        if (tid == 0) {
          __hip_atomic_store(flags + ((((unsigned)RG << 8) + t) << 3) + s, 1u,
                             __ATOMIC_RELAXED, __HIP_MEMORY_SCOPE_AGENT);
        }
      }
    }
    p ^= 1;
  }
}

// ---------------- K3: MLP head + softmax ---------------------------------------
__global__ __launch_bounds__(128) void mlp_kernel(
    const float* __restrict__ hfin, const float* __restrict__ W1,
    const float* __restrict__ b1, const float* __restrict__ W2,
    const float* __restrict__ b2, float* __restrict__ out) {
  __shared__ float hrow[512];
  __shared__ float act[128];
  __shared__ float lg[10];
  const int b = blockIdx.x;
  const int tid = threadIdx.x;
#pragma unroll
  for (int i = 0; i < 4; ++i)
    hrow[tid + i * 128] = hfin[(size_t)b * 512 + tid + i * 128];
  __syncthreads();
  float s = b1[tid];
#pragma unroll 8
  for (int k = 0; k < 512; ++k) s += hrow[k] * W1[(size_t)k * 128 + tid];
  act[tid] = fmaxf(s, 0.f);
  __syncthreads();
  if (tid < 10) {
    float l = b2[tid];
#pragma unroll 8
    for (int k = 0; k < 128; ++k) l += act[k] * W2[(size_t)k * 10 + tid];
    lg[tid] = l;
  }
  __syncthreads();
  if (tid == 0) {
    float m = lg[0];
    for (int j = 1; j < 10; ++j) m = fmaxf(m, lg[j]);
    float e[10];
    float sum = 0.f;
    for (int j = 0; j < 10; ++j) {
      e[j] = expf(lg[j] - m);
      sum += e[j];
    }
    float inv = 1.f / sum;
    for (int j = 0; j < 10; ++j) out[(size_t)b * 10 + j] = e[j] * inv;
  }
}

extern "C" void kernel_launch(void* const* d_in, const int* in_sizes, int n_in,
                              void* d_out, int out_size, void* d_ws,
                              size_t ws_size, hipStream_t stream) {
  const float* x    = (const float*)d_in[0];
  const float* Wx   = (const float*)d_in[1];
  const float* Wh   = (const float*)d_in[2];
  const float* bias = (const float*)d_in[3];
  const float* W1   = (const float*)d_in[4];
  const float* b1   = (const float*)d_in[5];
  const float* W2   = (const float*)d_in[6];
  const float* b2   = (const float*)d_in[7];
  float* out = (float*)d_out;

  char* ws = (char*)d_ws;
  // layout: [0,1MB) hbuf[2][512][512] bf16 | [1MB,+256KB) flags[32][256][8] |
  //         [2MB,+3MB) Wt bf16 | [5MB,+1MB) h_final f32
  unsigned short* hbuf = (unsigned short*)ws;
  unsigned* flags      = (unsigned*)(ws + 1048576);
  unsigned short* Wt   = (unsigned short*)(ws + 2097152);
  float* hfin          = (float*)(ws + 2097152 + 3145728);

  // zero h0 (parity 0) + flags; ws is re-poisoned 0xAA before every call
  hipMemsetAsync(d_ws, 0, 1048576 + 262144, stream);

  wt_kernel<<<dim3(64, 24), 256, 0, stream>>>(Wx, Wh, Wt);

  hipFuncSetAttribute((const void*)lstm_kernel,
                      hipFuncAttributeMaxDynamicSharedMemorySize, 98304);
  lstm_kernel<<<64, 256, 98304, stream>>>(x, Wt, bias, hbuf, flags, hfin);

  mlp_kernel<<<512, 128, 0, stream>>>(hfin, W1, b1, W2, b2, out);
}